// Round 1
// 1032.747 us; speedup vs baseline: 1.0015x; 1.0015x over previous
//
#include <hip/hip_runtime.h>
#include <math.h>

// Problem constants (S=8192 tokens, E=64 experts, capacity=256)
#define NTOK 8192
#define NEXP 64
#define CAP  256
#define SEC  (NTOK * NEXP * CAP)   // 134217728 floats per output tensor

// ---------------------------------------------------------------------------
// Kernel 1: per-token argmax (first-index tie-break) + softmax value at top1.
// One wave (64 lanes) per token row; lane e holds logit for expert e.
// ---------------------------------------------------------------------------
__global__ __launch_bounds__(256) void k_top1(const float* __restrict__ in,
                                              int* __restrict__ top1,
                                              float* __restrict__ val) {
    int wave = threadIdx.x >> 6;
    int lane = threadIdx.x & 63;
    int s = blockIdx.x * 4 + wave;
    float x = in[s * NEXP + lane];

    float bv = x;
    int   bi = lane;
#pragma unroll
    for (int off = 32; off > 0; off >>= 1) {
        float ov = __shfl_xor(bv, off);
        int   oi = __shfl_xor(bi, off);
        if (ov > bv || (ov == bv && oi < bi)) { bv = ov; bi = oi; }
    }
    float ex = expf(x - bv);
#pragma unroll
    for (int off = 32; off > 0; off >>= 1) ex += __shfl_xor(ex, off);

    if (lane == 0) {
        top1[s] = bi;
        val[s]  = 1.0f / ex;   // softmax value at the argmax
    }
}

// ---------------------------------------------------------------------------
// Kernel 2: deterministic per-expert exclusive rank via 6-ballot radix masks,
// FUSED with the sparse scatter. Single block, 16 waves; wave w owns tokens
// [w*512, w*512+512). The bulk zero-fill of the 1 GiB output now happens via
// hipMemsetAsync (rocclr fill path, measured 6.15-6.30 TB/s on this box) --
// this kernel only writes the <=8192 nonzero (val, 1.0f) pairs (~64 KiB).
// ---------------------------------------------------------------------------
__global__ __launch_bounds__(1024) void k_rank_scatter(const int* __restrict__ top1,
                                                       const float* __restrict__ val,
                                                       float* __restrict__ outc,
                                                       float* __restrict__ outm) {
    __shared__ int localrank[NTOK];      // 32 KB
    __shared__ int hist[16][64];
    __shared__ int chunkoff[16][64];

    int tid  = threadIdx.x;
    int w    = tid >> 6;
    int lane = tid & 63;
    int base = w * 512;

    int cnt = 0;  // lane l: tokens so far in this chunk routed to expert l
    for (int j0 = 0; j0 < 512; j0 += 64) {
        int e = top1[base + j0 + lane];
        unsigned long long b0 = __ballot((e & 1)  != 0);
        unsigned long long b1 = __ballot((e & 2)  != 0);
        unsigned long long b2 = __ballot((e & 4)  != 0);
        unsigned long long b3 = __ballot((e & 8)  != 0);
        unsigned long long b4 = __ballot((e & 16) != 0);
        unsigned long long b5 = __ballot((e & 32) != 0);
        unsigned long long my =
            ((e & 1)  ? b0 : ~b0) & ((e & 2)  ? b1 : ~b1) &
            ((e & 4)  ? b2 : ~b2) & ((e & 8)  ? b3 : ~b3) &
            ((e & 16) ? b4 : ~b4) & ((e & 32) ? b5 : ~b5);
        unsigned long long mb =
            ((lane & 1)  ? b0 : ~b0) & ((lane & 2)  ? b1 : ~b1) &
            ((lane & 4)  ? b2 : ~b2) & ((lane & 8)  ? b3 : ~b3) &
            ((lane & 16) ? b4 : ~b4) & ((lane & 32) ? b5 : ~b5);

        int lr  = __popcll(my & ((1ULL << lane) - 1ULL));  // rank within batch
        int off = __shfl(cnt, e);                           // earlier batches, same expert
        localrank[base + j0 + lane] = off + lr;
        cnt += __popcll(mb);
    }
    hist[w][lane] = cnt;
    __syncthreads();

    if (tid < 64) {  // lane-per-expert exclusive scan over 16 chunks
        int off = 0;
        for (int w2 = 0; w2 < 16; ++w2) {
            chunkoff[w2][tid] = off;
            off += hist[w2][tid];
        }
    }
    __syncthreads();

    // Sparse scatter: at most one nonzero per token row in each output tensor.
    // Row s, expert t, rank r -> flat index s*(E*C) + t*C + r.
    for (int s = tid; s < NTOK; s += 1024) {
        int t = top1[s];
        int r = localrank[s] + chunkoff[s >> 9][t];
        if (r < CAP) {
            size_t idx = (size_t)s * (NEXP * CAP) + (size_t)(t * CAP + r);
            outc[idx] = val[s];
            outm[idx] = 1.0f;
        }
    }
}

extern "C" void kernel_launch(void* const* d_in, const int* in_sizes, int n_in,
                              void* d_out, int out_size, void* d_ws, size_t ws_size,
                              hipStream_t stream) {
    const float* in = (const float*)d_in[0];

    // workspace: top1[8192] int | val[8192] float
    int*   top1 = (int*)d_ws;
    float* val  = (float*)((char*)d_ws + NTOK * 4);

    float* outc = (float*)d_out;
    float* outm = outc + (size_t)SEC;

    // Bulk zero of both output tensors (1 GiB contiguous) via the rocclr fill
    // path -- measured 6.15-6.30 TB/s on this box vs ~3.3 TB/s effective for
    // the previous hand-written fused fill kernel.
    hipMemsetAsync(d_out, 0, (size_t)SEC * 2 * sizeof(float), stream);

    hipLaunchKernelGGL(k_top1, dim3(NTOK / 4), dim3(256), 0, stream, in, top1, val);
    hipLaunchKernelGGL(k_rank_scatter, dim3(1), dim3(1024), 0, stream,
                       top1, val, outc, outm);
}